// Round 1
// baseline (452.759 us; speedup 1.0000x reference)
//
#include <hip/hip_runtime.h>

typedef __attribute__((ext_vector_type(8))) short short8;
typedef __attribute__((ext_vector_type(4))) float f32x4;

static __device__ __forceinline__ unsigned short f2bf(float f){
  unsigned u = __float_as_uint(f);
  u += 0x7FFF + ((u >> 16) & 1);
  return (unsigned short)(u >> 16);
}

// ---------------- fp32 -> bf16 convert (weights) ----------------
__global__ __launch_bounds__(256) void cvt_bf16(const float* __restrict__ in,
                                                unsigned short* __restrict__ out, int n4){
  int i = blockIdx.x * 256 + threadIdx.x;
  if (i < n4){
    float4 v = reinterpret_cast<const float4*>(in)[i];
    ushort4 o;
    o.x = f2bf(v.x); o.y = f2bf(v.y); o.z = f2bf(v.z); o.w = f2bf(v.w);
    reinterpret_cast<ushort4*>(out)[i] = o;
  }
}

// ---------------- LayerNorm fp32 -> bf16 ----------------
__global__ __launch_bounds__(256) void ln_bf16(const float* __restrict__ x,
    const float* __restrict__ g, const float* __restrict__ b,
    unsigned short* __restrict__ out){
  int row = blockIdx.x, t = threadIdx.x;
  const float* xr = x + (size_t)row * 1024;
  float4 xv = reinterpret_cast<const float4*>(xr)[t];
  float s  = xv.x + xv.y + xv.z + xv.w;
  float sq = xv.x*xv.x + xv.y*xv.y + xv.z*xv.z + xv.w*xv.w;
  #pragma unroll
  for (int m = 32; m >= 1; m >>= 1){ s += __shfl_xor(s, m); sq += __shfl_xor(sq, m); }
  __shared__ float ss[4], ssq[4];
  int w = t >> 6, lane = t & 63;
  if (lane == 0){ ss[w] = s; ssq[w] = sq; }
  __syncthreads();
  s  = ss[0] + ss[1] + ss[2] + ss[3];
  sq = ssq[0] + ssq[1] + ssq[2] + ssq[3];
  float mu = s * (1.f/1024.f);
  float rs = rsqrtf(sq * (1.f/1024.f) - mu*mu + 1e-5f);
  float4 gv = reinterpret_cast<const float4*>(g)[t];
  float4 bv = reinterpret_cast<const float4*>(b)[t];
  ushort4 o;
  o.x = f2bf((xv.x - mu) * rs * gv.x + bv.x);
  o.y = f2bf((xv.y - mu) * rs * gv.y + bv.y);
  o.z = f2bf((xv.z - mu) * rs * gv.z + bv.z);
  o.w = f2bf((xv.w - mu) * rs * gv.w + bv.w);
  reinterpret_cast<ushort4*>(out + (size_t)row * 1024)[t] = o;
}

// ---------------- GEMM: C[M,N] = epi(A[M,K] * B[N,K]^T + bias) ----------------
// EPI 0: bf16 out; 1: bf16 out + exact GELU; 2: fp32 out + residual add
template<int EPI>
__global__ __launch_bounds__(256) void gemm_bt(
    const unsigned short* __restrict__ A,
    const unsigned short* __restrict__ B,
    const float* __restrict__ bias,
    const float* __restrict__ resid,
    void* __restrict__ C,
    int M, int N, int K)
{
  __shared__ short As[128][72];
  __shared__ short Bs[128][72];
  int tid = threadIdx.x;
  int lane = tid & 63, wave = tid >> 6;
  int wm = wave >> 1, wn = wave & 1;
  int l15 = lane & 15, hi = lane >> 4;
  int bm = blockIdx.y * 128, bn = blockIdx.x * 128;
  int srow = tid >> 3, sseg = tid & 7;
  f32x4 acc[4][4] = {};
  for (int k0 = 0; k0 < K; k0 += 64){
    __syncthreads();
    #pragma unroll
    for (int i = 0; i < 4; i++){
      int r = i * 32 + srow;
      *reinterpret_cast<short8*>(&As[r][sseg * 8]) =
        *reinterpret_cast<const short8*>(A + (size_t)(bm + r) * K + k0 + sseg * 8);
      *reinterpret_cast<short8*>(&Bs[r][sseg * 8]) =
        *reinterpret_cast<const short8*>(B + (size_t)(bn + r) * K + k0 + sseg * 8);
    }
    __syncthreads();
    #pragma unroll
    for (int kk = 0; kk < 64; kk += 32){
      short8 af[4], bf[4];
      #pragma unroll
      for (int m = 0; m < 4; m++)
        af[m] = *reinterpret_cast<const short8*>(&As[wm*64 + m*16 + l15][kk + hi*8]);
      #pragma unroll
      for (int n = 0; n < 4; n++)
        bf[n] = *reinterpret_cast<const short8*>(&Bs[wn*64 + n*16 + l15][kk + hi*8]);
      #pragma unroll
      for (int m = 0; m < 4; m++)
        #pragma unroll
        for (int n = 0; n < 4; n++)
          acc[m][n] = __builtin_amdgcn_mfma_f32_16x16x32_bf16(af[m], bf[n], acc[m][n], 0, 0, 0);
    }
  }
  #pragma unroll
  for (int m = 0; m < 4; m++){
    int row = bm + wm*64 + m*16 + hi*4;
    #pragma unroll
    for (int n = 0; n < 4; n++){
      int col = bn + wn*64 + n*16 + l15;
      float bv = bias[col];
      #pragma unroll
      for (int j = 0; j < 4; j++){
        float v = acc[m][n][j] + bv;
        int r = row + j;
        if (EPI == 1) v = 0.5f * v * (1.f + erff(v * 0.70710678118654752f));
        if (EPI == 2){
          ((float*)C)[(size_t)r * N + col] = v + resid[(size_t)r * N + col];
        } else {
          ((unsigned short*)C)[(size_t)r * N + col] = f2bf(v);
        }
      }
    }
  }
}

// ---------------- Flash attention ----------------
// qkv: [B*2048, 3072] bf16, per-row layout [3, H=16, 64]; o: [B*2048, 1024] bf16
__global__ __launch_bounds__(256) void attn_fwd(const unsigned short* __restrict__ qkv,
                                                unsigned short* __restrict__ o){
  __shared__ short Ks[32][72];
  __shared__ short Vt[64][40];
  __shared__ short Ps[4][16][40];
  int tid = threadIdx.x, wave = tid >> 6, lane = tid & 63;
  int l15 = lane & 15, hi = lane >> 4;
  int qt = blockIdx.x, bh = blockIdx.y;
  int b = bh >> 4, h = bh & 15;
  const unsigned short* base  = qkv + (size_t)b * 2048 * 3072 + h * 64;
  const unsigned short* kbase = base + 1024;
  const unsigned short* vbase = base + 2048;
  int qrow = qt * 64 + wave * 16 + l15;
  short8 qf[2];
  qf[0] = *reinterpret_cast<const short8*>(base + (size_t)qrow * 3072 + hi * 8);
  qf[1] = *reinterpret_cast<const short8*>(base + (size_t)qrow * 3072 + 32 + hi * 8);
  float m_r[4], l_r[4];
  f32x4 accO[4] = {};
  #pragma unroll
  for (int j = 0; j < 4; j++){ m_r[j] = -1e30f; l_r[j] = 0.f; }
  int krow = tid >> 3, kseg = tid & 7;
  for (int kt = 0; kt < 2048; kt += 32){
    __syncthreads();
    *reinterpret_cast<short8*>(&Ks[krow][kseg * 8]) =
      *reinterpret_cast<const short8*>(kbase + (size_t)(kt + krow) * 3072 + kseg * 8);
    short8 vv = *reinterpret_cast<const short8*>(vbase + (size_t)(kt + krow) * 3072 + kseg * 8);
    #pragma unroll
    for (int j = 0; j < 8; j++) Vt[kseg * 8 + j][krow] = vv[j];
    __syncthreads();
    f32x4 s0 = {}, s1 = {};
    {
      short8 k0a = *reinterpret_cast<const short8*>(&Ks[l15][hi * 8]);
      short8 k0b = *reinterpret_cast<const short8*>(&Ks[l15][32 + hi * 8]);
      s0 = __builtin_amdgcn_mfma_f32_16x16x32_bf16(qf[0], k0a, s0, 0, 0, 0);
      s0 = __builtin_amdgcn_mfma_f32_16x16x32_bf16(qf[1], k0b, s0, 0, 0, 0);
      short8 k1a = *reinterpret_cast<const short8*>(&Ks[16 + l15][hi * 8]);
      short8 k1b = *reinterpret_cast<const short8*>(&Ks[16 + l15][32 + hi * 8]);
      s1 = __builtin_amdgcn_mfma_f32_16x16x32_bf16(qf[0], k1a, s1, 0, 0, 0);
      s1 = __builtin_amdgcn_mfma_f32_16x16x32_bf16(qf[1], k1b, s1, 0, 0, 0);
    }
    float p0[4], p1[4], corr[4];
    #pragma unroll
    for (int j = 0; j < 4; j++){
      float a = s0[j] * 0.125f, c = s1[j] * 0.125f;
      float mt = fmaxf(a, c);
      #pragma unroll
      for (int m = 1; m < 16; m <<= 1) mt = fmaxf(mt, __shfl_xor(mt, m));
      float mn = fmaxf(m_r[j], mt);
      corr[j] = __expf(m_r[j] - mn);
      p0[j] = __expf(a - mn);
      p1[j] = __expf(c - mn);
      float rs = p0[j] + p1[j];
      #pragma unroll
      for (int m = 1; m < 16; m <<= 1) rs += __shfl_xor(rs, m);
      l_r[j] = l_r[j] * corr[j] + rs;
      m_r[j] = mn;
    }
    #pragma unroll
    for (int dc = 0; dc < 4; dc++)
      #pragma unroll
      for (int j = 0; j < 4; j++) accO[dc][j] *= corr[j];
    #pragma unroll
    for (int j = 0; j < 4; j++){
      Ps[wave][hi * 4 + j][l15]      = (short)f2bf(p0[j]);
      Ps[wave][hi * 4 + j][16 + l15] = (short)f2bf(p1[j]);
    }
    asm volatile("s_waitcnt lgkmcnt(0)" ::: "memory");
    short8 pf = *reinterpret_cast<const short8*>(&Ps[wave][l15][hi * 8]);
    #pragma unroll
    for (int dc = 0; dc < 4; dc++){
      short8 vf = *reinterpret_cast<const short8*>(&Vt[dc * 16 + l15][hi * 8]);
      accO[dc] = __builtin_amdgcn_mfma_f32_16x16x32_bf16(pf, vf, accO[dc], 0, 0, 0);
    }
  }
  int orow = qt * 64 + wave * 16 + hi * 4;
  unsigned short* ob = o + (size_t)(b * 2048 + orow) * 1024 + h * 64;
  #pragma unroll
  for (int dc = 0; dc < 4; dc++)
    #pragma unroll
    for (int j = 0; j < 4; j++)
      ob[(size_t)j * 1024 + dc * 16 + l15] = f2bf(accO[dc][j] / l_r[j]);
}

extern "C" void kernel_launch(void* const* d_in, const int* in_sizes, int n_in,
                              void* d_out, int out_size, void* d_ws, size_t ws_size,
                              hipStream_t stream){
  const float* x      = (const float*)d_in[0];
  const float* ln1_g  = (const float*)d_in[1];
  const float* ln1_b  = (const float*)d_in[2];
  const float* w_qkv  = (const float*)d_in[3];
  const float* b_qkv  = (const float*)d_in[4];
  const float* w_proj = (const float*)d_in[5];
  const float* b_proj = (const float*)d_in[6];
  const float* ln2_g  = (const float*)d_in[7];
  const float* ln2_b  = (const float*)d_in[8];
  const float* w_fc1  = (const float*)d_in[9];
  const float* b_fc1  = (const float*)d_in[10];
  const float* w_fc2  = (const float*)d_in[11];
  const float* b_fc2  = (const float*)d_in[12];
  float* out = (float*)d_out;
  char* ws = (char*)d_ws;
  const size_t MB = 1024 * 1024;
  unsigned short* h     = (unsigned short*)(ws);            // 8 MB  [4096,1024] bf16
  unsigned short* qkv   = (unsigned short*)(ws + 8*MB);     // 24 MB [4096,3072] bf16
  unsigned short* ob    = (unsigned short*)(ws + 32*MB);    // 8 MB  [4096,1024] bf16
  float*          x1    = (float*)(ws + 40*MB);             // 16 MB [4096,1024] fp32
  unsigned short* f     = (unsigned short*)(ws + 56*MB);    // 32 MB [4096,4096] bf16
  unsigned short* wqkvb = (unsigned short*)(ws + 88*MB);    // 6 MB
  unsigned short* wprojb= (unsigned short*)(ws + 94*MB);    // 2 MB
  unsigned short* wfc1b = (unsigned short*)(ws + 96*MB);    // 8 MB
  unsigned short* wfc2b = (unsigned short*)(ws + 104*MB);   // 8 MB

  cvt_bf16<<<3072, 256, 0, stream>>>(w_qkv,  wqkvb,  3072*1024/4);
  cvt_bf16<<<1024, 256, 0, stream>>>(w_proj, wprojb, 1024*1024/4);
  cvt_bf16<<<4096, 256, 0, stream>>>(w_fc1,  wfc1b,  4096*1024/4);
  cvt_bf16<<<4096, 256, 0, stream>>>(w_fc2,  wfc2b,  1024*4096/4);

  ln_bf16<<<4096, 256, 0, stream>>>(x, ln1_g, ln1_b, h);
  gemm_bt<0><<<dim3(24, 32), 256, 0, stream>>>(h, wqkvb, b_qkv, nullptr, qkv, 4096, 3072, 1024);
  attn_fwd<<<dim3(32, 32), 256, 0, stream>>>(qkv, ob);
  gemm_bt<2><<<dim3(8, 32), 256, 0, stream>>>(ob, wprojb, b_proj, x, x1, 4096, 1024, 1024);
  ln_bf16<<<4096, 256, 0, stream>>>(x1, ln2_g, ln2_b, h);
  gemm_bt<1><<<dim3(32, 32), 256, 0, stream>>>(h, wfc1b, b_fc1, nullptr, f, 4096, 4096, 1024);
  gemm_bt<2><<<dim3(8, 32), 256, 0, stream>>>(f, wfc2b, b_fc2, x1, out, 4096, 1024, 4096);
}

// Round 2
// 322.766 us; speedup vs baseline: 1.4027x; 1.4027x over previous
//
#include <hip/hip_runtime.h>

typedef __attribute__((ext_vector_type(8))) short short8;
typedef __attribute__((ext_vector_type(4))) float f32x4;

static __device__ __forceinline__ unsigned short f2bf(float f){
  unsigned u = __float_as_uint(f);
  u += 0x7FFF + ((u >> 16) & 1);
  return (unsigned short)(u >> 16);
}

// ---------------- fp32 -> bf16 convert (weights) ----------------
__global__ __launch_bounds__(256) void cvt_bf16(const float* __restrict__ in,
                                                unsigned short* __restrict__ out, int n4){
  int i = blockIdx.x * 256 + threadIdx.x;
  if (i < n4){
    float4 v = reinterpret_cast<const float4*>(in)[i];
    ushort4 o;
    o.x = f2bf(v.x); o.y = f2bf(v.y); o.z = f2bf(v.z); o.w = f2bf(v.w);
    reinterpret_cast<ushort4*>(out)[i] = o;
  }
}

// ---------------- LayerNorm fp32 -> bf16 ----------------
__global__ __launch_bounds__(256) void ln_bf16(const float* __restrict__ x,
    const float* __restrict__ g, const float* __restrict__ b,
    unsigned short* __restrict__ out){
  int row = blockIdx.x, t = threadIdx.x;
  const float* xr = x + (size_t)row * 1024;
  float4 xv = reinterpret_cast<const float4*>(xr)[t];
  float s  = xv.x + xv.y + xv.z + xv.w;
  float sq = xv.x*xv.x + xv.y*xv.y + xv.z*xv.z + xv.w*xv.w;
  #pragma unroll
  for (int m = 32; m >= 1; m >>= 1){ s += __shfl_xor(s, m); sq += __shfl_xor(sq, m); }
  __shared__ float ss[4], ssq[4];
  int w = t >> 6, lane = t & 63;
  if (lane == 0){ ss[w] = s; ssq[w] = sq; }
  __syncthreads();
  s  = ss[0] + ss[1] + ss[2] + ss[3];
  sq = ssq[0] + ssq[1] + ssq[2] + ssq[3];
  float mu = s * (1.f/1024.f);
  float rs = rsqrtf(sq * (1.f/1024.f) - mu*mu + 1e-5f);
  float4 gv = reinterpret_cast<const float4*>(g)[t];
  float4 bv = reinterpret_cast<const float4*>(b)[t];
  ushort4 o;
  o.x = f2bf((xv.x - mu) * rs * gv.x + bv.x);
  o.y = f2bf((xv.y - mu) * rs * gv.y + bv.y);
  o.z = f2bf((xv.z - mu) * rs * gv.z + bv.z);
  o.w = f2bf((xv.w - mu) * rs * gv.w + bv.w);
  reinterpret_cast<ushort4*>(out + (size_t)row * 1024)[t] = o;
}

// ---------------- GEMM: C[M,N] = epi(A[M,K] * B[N,K]^T + bias) ----------------
template<int EPI>
__global__ __launch_bounds__(256) void gemm_bt(
    const unsigned short* __restrict__ A,
    const unsigned short* __restrict__ B,
    const float* __restrict__ bias,
    const float* __restrict__ resid,
    void* __restrict__ C,
    int M, int N, int K)
{
  __shared__ short As[128][72];
  __shared__ short Bs[128][72];
  int tid = threadIdx.x;
  int lane = tid & 63, wave = tid >> 6;
  int wm = wave >> 1, wn = wave & 1;
  int l15 = lane & 15, hi = lane >> 4;
  int bm = blockIdx.y * 128, bn = blockIdx.x * 128;
  int srow = tid >> 3, sseg = tid & 7;
  f32x4 acc[4][4] = {};
  for (int k0 = 0; k0 < K; k0 += 64){
    __syncthreads();
    #pragma unroll
    for (int i = 0; i < 4; i++){
      int r = i * 32 + srow;
      *reinterpret_cast<short8*>(&As[r][sseg * 8]) =
        *reinterpret_cast<const short8*>(A + (size_t)(bm + r) * K + k0 + sseg * 8);
      *reinterpret_cast<short8*>(&Bs[r][sseg * 8]) =
        *reinterpret_cast<const short8*>(B + (size_t)(bn + r) * K + k0 + sseg * 8);
    }
    __syncthreads();
    #pragma unroll
    for (int kk = 0; kk < 64; kk += 32){
      short8 af[4], bf[4];
      #pragma unroll
      for (int m = 0; m < 4; m++)
        af[m] = *reinterpret_cast<const short8*>(&As[wm*64 + m*16 + l15][kk + hi*8]);
      #pragma unroll
      for (int n = 0; n < 4; n++)
        bf[n] = *reinterpret_cast<const short8*>(&Bs[wn*64 + n*16 + l15][kk + hi*8]);
      #pragma unroll
      for (int m = 0; m < 4; m++)
        #pragma unroll
        for (int n = 0; n < 4; n++)
          acc[m][n] = __builtin_amdgcn_mfma_f32_16x16x32_bf16(af[m], bf[n], acc[m][n], 0, 0, 0);
    }
  }
  #pragma unroll
  for (int m = 0; m < 4; m++){
    int row = bm + wm*64 + m*16 + hi*4;
    #pragma unroll
    for (int n = 0; n < 4; n++){
      int col = bn + wn*64 + n*16 + l15;
      float bv = bias[col];
      #pragma unroll
      for (int j = 0; j < 4; j++){
        float v = acc[m][n][j] + bv;
        int r = row + j;
        if (EPI == 1) v = 0.5f * v * (1.f + erff(v * 0.70710678118654752f));
        if (EPI == 2){
          ((float*)C)[(size_t)r * N + col] = v + resid[(size_t)r * N + col];
        } else {
          ((unsigned short*)C)[(size_t)r * N + col] = f2bf(v);
        }
      }
    }
  }
}

// ---------------- Flash attention (swapped QK^T, S^T lane-local softmax) ----------------
// qkv: [B*2048, 3072] bf16 rows = [q 1024 | k 1024 | v 1024], head-major inside; o: [B*2048,1024]
__global__ __launch_bounds__(256) void attn_fwd(const unsigned short* __restrict__ qkv,
                                                unsigned short* __restrict__ o){
  __shared__ __attribute__((aligned(16))) short K_lds[2][64*64];
  __shared__ __attribute__((aligned(16))) short V_lds[2][64*64];   // V^T
  __shared__ __attribute__((aligned(16))) short P_lds[4][16*64];
  int tid = threadIdx.x, wave = tid >> 6, lane = tid & 63;
  int l15 = lane & 15, hi = lane >> 4, l7 = l15 & 7;
  int qt = blockIdx.x, bh = blockIdx.y;
  int b = bh >> 4, h = bh & 15;
  const unsigned short* qbase = qkv + (size_t)b * 2048 * 3072 + h * 64;
  const unsigned short* kbase = qbase + 1024;
  const unsigned short* vbase = qbase + 2048;
  int qrow = qt * 64 + wave * 16 + l15;
  short8 qf0 = *(const short8*)(qbase + (size_t)qrow * 3072 + hi * 8);
  short8 qf1 = *(const short8*)(qbase + (size_t)qrow * 3072 + 32 + hi * 8);
  // V staging: this thread handles k rows {2kp, 2kp+1}, d = ds8*8..+7
  int kp = tid & 31, ds8 = tid >> 5;
  int vcg = kp >> 2, vwi = (2 * kp) & 7;
  float m_r = -1e30f, l_r = 0.f;
  f32x4 accO[4] = {};
  short* Pw = &P_lds[wave][0];

  // prologue: stage tile 0 into buffer 0
  {
    short8 kv0[2], vv0, vv1;
    #pragma unroll
    for (int r = 0; r < 2; r++){
      int g = r * 256 + tid, row = g >> 3, cg = g & 7;
      kv0[r] = *(const short8*)(kbase + (size_t)row * 3072 + cg * 8);
    }
    const unsigned short* vr = vbase + (size_t)(2 * kp) * 3072 + ds8 * 8;
    vv0 = *(const short8*)vr; vv1 = *(const short8*)(vr + 3072);
    #pragma unroll
    for (int r = 0; r < 2; r++){
      int g = r * 256 + tid, row = g >> 3, cg = g & 7;
      *(short8*)(&K_lds[0][row * 64 + ((cg ^ (row & 7)) << 3)]) = kv0[r];
    }
    unsigned* Vw = (unsigned*)&V_lds[0][0];
    #pragma unroll
    for (int j = 0; j < 8; j++){
      int d = ds8 * 8 + j;
      int sa = d * 64 + ((vcg ^ (d & 7)) << 3) + vwi;
      Vw[sa >> 1] = (unsigned)(unsigned short)vv0[j] | ((unsigned)(unsigned short)vv1[j] << 16);
    }
    __syncthreads();
  }

  for (int t = 0; t < 32; t++){
    int cur = t & 1;
    const short* Kc = &K_lds[cur][0];
    const short* Vc = &V_lds[cur][0];
    // issue next-tile global loads early (T14: latency hides under compute)
    short8 kv0, kv1, vv0, vv1;
    if (t < 31){
      int kt = (t + 1) * 64;
      { int g = tid,       row = g >> 3, cg = g & 7;
        kv0 = *(const short8*)(kbase + (size_t)(kt + row) * 3072 + cg * 8); }
      { int g = 256 + tid, row = g >> 3, cg = g & 7;
        kv1 = *(const short8*)(kbase + (size_t)(kt + row) * 3072 + cg * 8); }
      const unsigned short* vr = vbase + (size_t)(kt + 2 * kp) * 3072 + ds8 * 8;
      vv0 = *(const short8*)vr; vv1 = *(const short8*)(vr + 3072);
    }
    // S^T[k][q] = sum_d K[k][d] Q[q][d]
    f32x4 sacc[4];
    #pragma unroll
    for (int kb = 0; kb < 4; kb++){
      f32x4 s = {};
      short8 ka = *(const short8*)(Kc + (kb * 16 + l15) * 64 + ((hi ^ l7) << 3));
      s = __builtin_amdgcn_mfma_f32_16x16x32_bf16(ka, qf0, s, 0, 0, 0);
      short8 kb_ = *(const short8*)(Kc + (kb * 16 + l15) * 64 + (((4 + hi) ^ l7) << 3));
      s = __builtin_amdgcn_mfma_f32_16x16x32_bf16(kb_, qf1, s, 0, 0, 0);
      sacc[kb] = s;
    }
    // per-lane softmax: 16 k-values in-lane, q = l15; cross-hi via 2 shuffles
    float sv[16];
    #pragma unroll
    for (int kb = 0; kb < 4; kb++)
      #pragma unroll
      for (int r2 = 0; r2 < 4; r2++) sv[kb * 4 + r2] = sacc[kb][r2] * 0.125f;
    float m01 = fmaxf(fmaxf(sv[0], sv[1]), fmaxf(sv[2], sv[3]));
    float m23 = fmaxf(fmaxf(sv[4], sv[5]), fmaxf(sv[6], sv[7]));
    float m45 = fmaxf(fmaxf(sv[8], sv[9]), fmaxf(sv[10], sv[11]));
    float m67 = fmaxf(fmaxf(sv[12], sv[13]), fmaxf(sv[14], sv[15]));
    float mt = fmaxf(fmaxf(m01, m23), fmaxf(m45, m67));
    mt = fmaxf(mt, __shfl_xor(mt, 16));
    mt = fmaxf(mt, __shfl_xor(mt, 32));
    float mn = fmaxf(m_r, mt);
    float corr = __expf(m_r - mn);
    m_r = mn;
    float rs = 0.f;
    unsigned pu[8];
    #pragma unroll
    for (int i = 0; i < 16; i += 2){
      float p0 = __expf(sv[i] - mn), p1 = __expf(sv[i + 1] - mn);
      rs += p0 + p1;
      pu[i >> 1] = (unsigned)f2bf(p0) | ((unsigned)f2bf(p1) << 16);
    }
    rs += __shfl_xor(rs, 16);
    rs += __shfl_xor(rs, 32);
    l_r = l_r * corr + rs;
    #pragma unroll
    for (int db = 0; db < 4; db++)
      #pragma unroll
      for (int r2 = 0; r2 < 4; r2++) accO[db][r2] *= corr;
    // write P[q=l15][k]: 4x ds_write_b64, swizzled
    #pragma unroll
    for (int kb = 0; kb < 4; kb++){
      int sa = l15 * 64 + ((((kb << 1) | (hi >> 1)) ^ l7) << 3) + ((hi & 1) << 2);
      *(uint2*)(Pw + sa) = make_uint2(pu[kb * 2], pu[kb * 2 + 1]);
    }
    // O^T[d][q] += sum_k V^T[d][k] P[q][k]
    #pragma unroll
    for (int kb2 = 0; kb2 < 2; kb2++){
      short8 pf = *(const short8*)(Pw + l15 * 64 + ((((kb2 << 2) | hi) ^ l7) << 3));
      #pragma unroll
      for (int db = 0; db < 4; db++){
        short8 vf = *(const short8*)(Vc + (db * 16 + l15) * 64 + ((((kb2 << 2) | hi) ^ l7) << 3));
        accO[db] = __builtin_amdgcn_mfma_f32_16x16x32_bf16(vf, pf, accO[db], 0, 0, 0);
      }
    }
    // write next tile to LDS, single barrier
    if (t < 31){
      int nxt = cur ^ 1;
      { int g = tid,       row = g >> 3, cg = g & 7;
        *(short8*)(&K_lds[nxt][row * 64 + ((cg ^ (row & 7)) << 3)]) = kv0; }
      { int g = 256 + tid, row = g >> 3, cg = g & 7;
        *(short8*)(&K_lds[nxt][row * 64 + ((cg ^ (row & 7)) << 3)]) = kv1; }
      unsigned* Vw = (unsigned*)&V_lds[nxt][0];
      #pragma unroll
      for (int j = 0; j < 8; j++){
        int d = ds8 * 8 + j;
        int sa = d * 64 + ((vcg ^ (d & 7)) << 3) + vwi;
        Vw[sa >> 1] = (unsigned)(unsigned short)vv0[j] | ((unsigned)(unsigned short)vv1[j] << 16);
      }
      __syncthreads();
    }
  }
  // epilogue: lane holds O^T[d = db*16+hi*4+r][q = l15]
  float inv = 1.f / l_r;
  unsigned short* ob = o + (size_t)(b * 2048 + qt * 64 + wave * 16 + l15) * 1024 + h * 64;
  #pragma unroll
  for (int db = 0; db < 4; db++){
    ushort4 w;
    w.x = f2bf(accO[db][0] * inv);
    w.y = f2bf(accO[db][1] * inv);
    w.z = f2bf(accO[db][2] * inv);
    w.w = f2bf(accO[db][3] * inv);
    *(ushort4*)(ob + db * 16 + hi * 4) = w;
  }
}

extern "C" void kernel_launch(void* const* d_in, const int* in_sizes, int n_in,
                              void* d_out, int out_size, void* d_ws, size_t ws_size,
                              hipStream_t stream){
  const float* x      = (const float*)d_in[0];
  const float* ln1_g  = (const float*)d_in[1];
  const float* ln1_b  = (const float*)d_in[2];
  const float* w_qkv  = (const float*)d_in[3];
  const float* b_qkv  = (const float*)d_in[4];
  const float* w_proj = (const float*)d_in[5];
  const float* b_proj = (const float*)d_in[6];
  const float* ln2_g  = (const float*)d_in[7];
  const float* ln2_b  = (const float*)d_in[8];
  const float* w_fc1  = (const float*)d_in[9];
  const float* b_fc1  = (const float*)d_in[10];
  const float* w_fc2  = (const float*)d_in[11];
  const float* b_fc2  = (const float*)d_in[12];
  float* out = (float*)d_out;
  char* ws = (char*)d_ws;
  const size_t MB = 1024 * 1024;
  unsigned short* h     = (unsigned short*)(ws);            // 8 MB  [4096,1024] bf16
  unsigned short* qkv   = (unsigned short*)(ws + 8*MB);     // 24 MB [4096,3072] bf16
  unsigned short* ob    = (unsigned short*)(ws + 32*MB);    // 8 MB  [4096,1024] bf16
  float*          x1    = (float*)(ws + 40*MB);             // 16 MB [4096,1024] fp32
  unsigned short* f     = (unsigned short*)(ws + 56*MB);    // 32 MB [4096,4096] bf16
  unsigned short* wqkvb = (unsigned short*)(ws + 88*MB);    // 6 MB
  unsigned short* wprojb= (unsigned short*)(ws + 94*MB);    // 2 MB
  unsigned short* wfc1b = (unsigned short*)(ws + 96*MB);    // 8 MB
  unsigned short* wfc2b = (unsigned short*)(ws + 104*MB);   // 8 MB

  cvt_bf16<<<3072, 256, 0, stream>>>(w_qkv,  wqkvb,  3072*1024/4);
  cvt_bf16<<<1024, 256, 0, stream>>>(w_proj, wprojb, 1024*1024/4);
  cvt_bf16<<<4096, 256, 0, stream>>>(w_fc1,  wfc1b,  4096*1024/4);
  cvt_bf16<<<4096, 256, 0, stream>>>(w_fc2,  wfc2b,  1024*4096/4);

  ln_bf16<<<4096, 256, 0, stream>>>(x, ln1_g, ln1_b, h);
  gemm_bt<0><<<dim3(24, 32), 256, 0, stream>>>(h, wqkvb, b_qkv, nullptr, qkv, 4096, 3072, 1024);
  attn_fwd<<<dim3(32, 32), 256, 0, stream>>>(qkv, ob);
  gemm_bt<2><<<dim3(8, 32), 256, 0, stream>>>(ob, wprojb, b_proj, x, x1, 4096, 1024, 1024);
  ln_bf16<<<4096, 256, 0, stream>>>(x1, ln2_g, ln2_b, h);
  gemm_bt<1><<<dim3(32, 32), 256, 0, stream>>>(h, wfc1b, b_fc1, nullptr, f, 4096, 4096, 1024);
  gemm_bt<2><<<dim3(8, 32), 256, 0, stream>>>(f, wfc2b, b_fc2, x1, out, 4096, 1024, 4096);
}

// Round 3
// 315.726 us; speedup vs baseline: 1.4340x; 1.0223x over previous
//
#include <hip/hip_runtime.h>

typedef __attribute__((ext_vector_type(8))) short short8;
typedef __attribute__((ext_vector_type(4))) float f32x4;

static __device__ __forceinline__ unsigned short f2bf(float f){
  unsigned u = __float_as_uint(f);
  u += 0x7FFF + ((u >> 16) & 1);
  return (unsigned short)(u >> 16);
}

#define GL16(g, l) __builtin_amdgcn_global_load_lds( \
    (const __attribute__((address_space(1))) void*)(g), \
    (__attribute__((address_space(3))) void*)(l), 16, 0, 0)

// ---------------- fp32 -> bf16 convert (weights) ----------------
__global__ __launch_bounds__(256) void cvt_bf16(const float* __restrict__ in,
                                                unsigned short* __restrict__ out, int n4){
  int i = blockIdx.x * 256 + threadIdx.x;
  if (i < n4){
    float4 v = reinterpret_cast<const float4*>(in)[i];
    ushort4 o;
    o.x = f2bf(v.x); o.y = f2bf(v.y); o.z = f2bf(v.z); o.w = f2bf(v.w);
    reinterpret_cast<ushort4*>(out)[i] = o;
  }
}

// ---------------- LayerNorm fp32 -> bf16 ----------------
__global__ __launch_bounds__(256) void ln_bf16(const float* __restrict__ x,
    const float* __restrict__ g, const float* __restrict__ b,
    unsigned short* __restrict__ out){
  int row = blockIdx.x, t = threadIdx.x;
  const float* xr = x + (size_t)row * 1024;
  float4 xv = reinterpret_cast<const float4*>(xr)[t];
  float s  = xv.x + xv.y + xv.z + xv.w;
  float sq = xv.x*xv.x + xv.y*xv.y + xv.z*xv.z + xv.w*xv.w;
  #pragma unroll
  for (int m = 32; m >= 1; m >>= 1){ s += __shfl_xor(s, m); sq += __shfl_xor(sq, m); }
  __shared__ float ss[4], ssq[4];
  int w = t >> 6, lane = t & 63;
  if (lane == 0){ ss[w] = s; ssq[w] = sq; }
  __syncthreads();
  s  = ss[0] + ss[1] + ss[2] + ss[3];
  sq = ssq[0] + ssq[1] + ssq[2] + ssq[3];
  float mu = s * (1.f/1024.f);
  float rs = rsqrtf(sq * (1.f/1024.f) - mu*mu + 1e-5f);
  float4 gv = reinterpret_cast<const float4*>(g)[t];
  float4 bv = reinterpret_cast<const float4*>(b)[t];
  ushort4 o;
  o.x = f2bf((xv.x - mu) * rs * gv.x + bv.x);
  o.y = f2bf((xv.y - mu) * rs * gv.y + bv.y);
  o.z = f2bf((xv.z - mu) * rs * gv.z + bv.z);
  o.w = f2bf((xv.w - mu) * rs * gv.w + bv.w);
  reinterpret_cast<ushort4*>(out + (size_t)row * 1024)[t] = o;
}

// ---------------- GEMM: C[M,N] = epi(A[M,K] * B[N,K]^T + bias) ----------------
// TM x 128 tile, BK=64, 4 waves, global_load_lds staging (m97 structure).
// EPI 0: bf16 out; 1: bf16 out + exact GELU; 2: fp32 out + residual add
template<int TM, int EPI>
__global__ __launch_bounds__(256) void gemm_bt(
    const unsigned short* __restrict__ A,
    const unsigned short* __restrict__ B,
    const float* __restrict__ bias,
    const float* __restrict__ resid,
    void* __restrict__ C,
    int M, int N, int K)
{
  constexpr int MR = TM / 32;           // row fragments per wave
  __shared__ __attribute__((aligned(16))) short As[TM * 64];
  __shared__ __attribute__((aligned(16))) short Bs[128 * 64];
  int tid = threadIdx.x;
  int lane = tid & 63, wave = tid >> 6;
  int wm = wave >> 1, wn = wave & 1;
  int l15 = lane & 15, hi = lane >> 4;
  int bm = blockIdx.y * TM, bn = blockIdx.x * 128;
  int lr = lane >> 3, lseg = lane & 7;   // staging: 8 rows x 8 segs per load
  f32x4 acc[MR][4] = {};
  for (int k0 = 0; k0 < K; k0 += 64){
    __syncthreads();
    #pragma unroll
    for (int j = 0; j < TM / 32; j++){
      int br = (wave * (TM / 32) + j) * 8;
      GL16(A + (size_t)(bm + br + lr) * K + k0 + lseg * 8, &As[br * 64]);
    }
    #pragma unroll
    for (int j = 0; j < 4; j++){
      int br = (wave * 4 + j) * 8;
      GL16(B + (size_t)(bn + br + lr) * K + k0 + lseg * 8, &Bs[br * 64]);
    }
    __syncthreads();
    #pragma unroll
    for (int kk = 0; kk < 64; kk += 32){
      short8 af[MR], bf[4];
      #pragma unroll
      for (int m = 0; m < MR; m++)
        af[m] = *reinterpret_cast<const short8*>(&As[(wm*(TM/2) + m*16 + l15) * 64 + kk + hi*8]);
      #pragma unroll
      for (int n = 0; n < 4; n++)
        bf[n] = *reinterpret_cast<const short8*>(&Bs[(wn*64 + n*16 + l15) * 64 + kk + hi*8]);
      #pragma unroll
      for (int m = 0; m < MR; m++)
        #pragma unroll
        for (int n = 0; n < 4; n++)
          acc[m][n] = __builtin_amdgcn_mfma_f32_16x16x32_bf16(af[m], bf[n], acc[m][n], 0, 0, 0);
    }
  }
  #pragma unroll
  for (int m = 0; m < MR; m++){
    int row = bm + wm*(TM/2) + m*16 + hi*4;
    #pragma unroll
    for (int n = 0; n < 4; n++){
      int col = bn + wn*64 + n*16 + l15;
      float bv = bias[col];
      #pragma unroll
      for (int j = 0; j < 4; j++){
        float v = acc[m][n][j] + bv;
        int r = row + j;
        if (EPI == 1) v = 0.5f * v * (1.f + erff(v * 0.70710678118654752f));
        if (EPI == 2){
          ((float*)C)[(size_t)r * N + col] = v + resid[(size_t)r * N + col];
        } else {
          ((unsigned short*)C)[(size_t)r * N + col] = f2bf(v);
        }
      }
    }
  }
}

// ---------------- Flash attention (swapped QK^T, S^T lane-local softmax) ----------------
// qkv: [B*2048, 3072] bf16 rows = [q 1024 | k 1024 | v 1024], head-major inside; o: [B*2048,1024]
__global__ __launch_bounds__(256) void attn_fwd(const unsigned short* __restrict__ qkv,
                                                unsigned short* __restrict__ o){
  __shared__ __attribute__((aligned(16))) short K_lds[2][64*64];
  __shared__ __attribute__((aligned(16))) short V_lds[2][64*64];   // V^T
  __shared__ __attribute__((aligned(16))) short P_lds[4][16*64];
  int tid = threadIdx.x, wave = tid >> 6, lane = tid & 63;
  int l15 = lane & 15, hi = lane >> 4, l7 = l15 & 7;
  int qt = blockIdx.x, bh = blockIdx.y;
  int b = bh >> 4, h = bh & 15;
  const unsigned short* qbase = qkv + (size_t)b * 2048 * 3072 + h * 64;
  const unsigned short* kbase = qbase + 1024;
  const unsigned short* vbase = qbase + 2048;
  int qrow = qt * 64 + wave * 16 + l15;
  short8 qf0 = *(const short8*)(qbase + (size_t)qrow * 3072 + hi * 8);
  short8 qf1 = *(const short8*)(qbase + (size_t)qrow * 3072 + 32 + hi * 8);
  int kp = tid & 31, ds8 = tid >> 5;
  int vcg = kp >> 2, vwi = (2 * kp) & 7;
  float m_r = -1e30f, l_r = 0.f;
  f32x4 accO[4] = {};
  short* Pw = &P_lds[wave][0];

  // prologue: stage tile 0 into buffer 0
  {
    short8 kv0[2], vv0, vv1;
    #pragma unroll
    for (int r = 0; r < 2; r++){
      int g = r * 256 + tid, row = g >> 3, cg = g & 7;
      kv0[r] = *(const short8*)(kbase + (size_t)row * 3072 + cg * 8);
    }
    const unsigned short* vr = vbase + (size_t)(2 * kp) * 3072 + ds8 * 8;
    vv0 = *(const short8*)vr; vv1 = *(const short8*)(vr + 3072);
    #pragma unroll
    for (int r = 0; r < 2; r++){
      int g = r * 256 + tid, row = g >> 3, cg = g & 7;
      *(short8*)(&K_lds[0][row * 64 + ((cg ^ (row & 7)) << 3)]) = kv0[r];
    }
    unsigned* Vw = (unsigned*)&V_lds[0][0];
    #pragma unroll
    for (int j = 0; j < 8; j++){
      int d = ds8 * 8 + j;
      int sa = d * 64 + ((vcg ^ (d & 7)) << 3) + vwi;
      Vw[sa >> 1] = (unsigned)(unsigned short)vv0[j] | ((unsigned)(unsigned short)vv1[j] << 16);
    }
    __syncthreads();
  }

  for (int t = 0; t < 32; t++){
    int cur = t & 1;
    const short* Kc = &K_lds[cur][0];
    const short* Vc = &V_lds[cur][0];
    // issue next-tile global loads early (T14: latency hides under compute)
    short8 kv0, kv1, vv0, vv1;
    if (t < 31){
      int kt = (t + 1) * 64;
      { int g = tid,       row = g >> 3, cg = g & 7;
        kv0 = *(const short8*)(kbase + (size_t)(kt + row) * 3072 + cg * 8); }
      { int g = 256 + tid, row = g >> 3, cg = g & 7;
        kv1 = *(const short8*)(kbase + (size_t)(kt + row) * 3072 + cg * 8); }
      const unsigned short* vr = vbase + (size_t)(kt + 2 * kp) * 3072 + ds8 * 8;
      vv0 = *(const short8*)vr; vv1 = *(const short8*)(vr + 3072);
    }
    // S^T[k][q] = sum_d K[k][d] Q[q][d]
    f32x4 sacc[4];
    __builtin_amdgcn_s_setprio(1);
    #pragma unroll
    for (int kb = 0; kb < 4; kb++){
      f32x4 s = {};
      short8 ka = *(const short8*)(Kc + (kb * 16 + l15) * 64 + ((hi ^ l7) << 3));
      s = __builtin_amdgcn_mfma_f32_16x16x32_bf16(ka, qf0, s, 0, 0, 0);
      short8 kb_ = *(const short8*)(Kc + (kb * 16 + l15) * 64 + (((4 + hi) ^ l7) << 3));
      s = __builtin_amdgcn_mfma_f32_16x16x32_bf16(kb_, qf1, s, 0, 0, 0);
      sacc[kb] = s;
    }
    __builtin_amdgcn_s_setprio(0);
    // per-lane softmax: 16 k-values in-lane, q = l15; cross-hi via 2 shuffles
    float sv[16];
    #pragma unroll
    for (int kb = 0; kb < 4; kb++)
      #pragma unroll
      for (int r2 = 0; r2 < 4; r2++) sv[kb * 4 + r2] = sacc[kb][r2] * 0.125f;
    float m01 = fmaxf(fmaxf(sv[0], sv[1]), fmaxf(sv[2], sv[3]));
    float m23 = fmaxf(fmaxf(sv[4], sv[5]), fmaxf(sv[6], sv[7]));
    float m45 = fmaxf(fmaxf(sv[8], sv[9]), fmaxf(sv[10], sv[11]));
    float m67 = fmaxf(fmaxf(sv[12], sv[13]), fmaxf(sv[14], sv[15]));
    float mt = fmaxf(fmaxf(m01, m23), fmaxf(m45, m67));
    mt = fmaxf(mt, __shfl_xor(mt, 16));
    mt = fmaxf(mt, __shfl_xor(mt, 32));
    // defer-max (T13): only rescale when the running max grew by > 8
    if (!__all(mt - m_r <= 8.f)){
      float mn = fmaxf(m_r, mt);
      float corr = __expf(m_r - mn);
      m_r = mn;
      l_r *= corr;
      #pragma unroll
      for (int db = 0; db < 4; db++)
        #pragma unroll
        for (int r2 = 0; r2 < 4; r2++) accO[db][r2] *= corr;
    }
    float rs = 0.f;
    unsigned pu[8];
    #pragma unroll
    for (int i = 0; i < 16; i += 2){
      float p0 = __expf(sv[i] - m_r), p1 = __expf(sv[i + 1] - m_r);
      rs += p0 + p1;
      pu[i >> 1] = (unsigned)f2bf(p0) | ((unsigned)f2bf(p1) << 16);
    }
    rs += __shfl_xor(rs, 16);
    rs += __shfl_xor(rs, 32);
    l_r += rs;
    // write P[q=l15][k]: 4x ds_write_b64, swizzled
    #pragma unroll
    for (int kb = 0; kb < 4; kb++){
      int sa = l15 * 64 + ((((kb << 1) | (hi >> 1)) ^ l7) << 3) + ((hi & 1) << 2);
      *(uint2*)(Pw + sa) = make_uint2(pu[kb * 2], pu[kb * 2 + 1]);
    }
    // O^T[d][q] += sum_k V^T[d][k] P[q][k]
    __builtin_amdgcn_s_setprio(1);
    #pragma unroll
    for (int kb2 = 0; kb2 < 2; kb2++){
      short8 pf = *(const short8*)(Pw + l15 * 64 + ((((kb2 << 2) | hi) ^ l7) << 3));
      #pragma unroll
      for (int db = 0; db < 4; db++){
        short8 vf = *(const short8*)(Vc + (db * 16 + l15) * 64 + ((((kb2 << 2) | hi) ^ l7) << 3));
        accO[db] = __builtin_amdgcn_mfma_f32_16x16x32_bf16(vf, pf, accO[db], 0, 0, 0);
      }
    }
    __builtin_amdgcn_s_setprio(0);
    // write next tile to LDS, single barrier
    if (t < 31){
      int nxt = cur ^ 1;
      { int g = tid,       row = g >> 3, cg = g & 7;
        *(short8*)(&K_lds[nxt][row * 64 + ((cg ^ (row & 7)) << 3)]) = kv0; }
      { int g = 256 + tid, row = g >> 3, cg = g & 7;
        *(short8*)(&K_lds[nxt][row * 64 + ((cg ^ (row & 7)) << 3)]) = kv1; }
      unsigned* Vw = (unsigned*)&V_lds[nxt][0];
      #pragma unroll
      for (int j = 0; j < 8; j++){
        int d = ds8 * 8 + j;
        int sa = d * 64 + ((vcg ^ (d & 7)) << 3) + vwi;
        Vw[sa >> 1] = (unsigned)(unsigned short)vv0[j] | ((unsigned)(unsigned short)vv1[j] << 16);
      }
      __syncthreads();
    }
  }
  // epilogue: lane holds O^T[d = db*16+hi*4+r][q = l15]
  float inv = 1.f / l_r;
  unsigned short* ob = o + (size_t)(b * 2048 + qt * 64 + wave * 16 + l15) * 1024 + h * 64;
  #pragma unroll
  for (int db = 0; db < 4; db++){
    ushort4 w;
    w.x = f2bf(accO[db][0] * inv);
    w.y = f2bf(accO[db][1] * inv);
    w.z = f2bf(accO[db][2] * inv);
    w.w = f2bf(accO[db][3] * inv);
    *(ushort4*)(ob + db * 16 + hi * 4) = w;
  }
}

extern "C" void kernel_launch(void* const* d_in, const int* in_sizes, int n_in,
                              void* d_out, int out_size, void* d_ws, size_t ws_size,
                              hipStream_t stream){
  const float* x      = (const float*)d_in[0];
  const float* ln1_g  = (const float*)d_in[1];
  const float* ln1_b  = (const float*)d_in[2];
  const float* w_qkv  = (const float*)d_in[3];
  const float* b_qkv  = (const float*)d_in[4];
  const float* w_proj = (const float*)d_in[5];
  const float* b_proj = (const float*)d_in[6];
  const float* ln2_g  = (const float*)d_in[7];
  const float* ln2_b  = (const float*)d_in[8];
  const float* w_fc1  = (const float*)d_in[9];
  const float* b_fc1  = (const float*)d_in[10];
  const float* w_fc2  = (const float*)d_in[11];
  const float* b_fc2  = (const float*)d_in[12];
  float* out = (float*)d_out;
  char* ws = (char*)d_ws;
  const size_t MB = 1024 * 1024;
  unsigned short* h     = (unsigned short*)(ws);            // 8 MB  [4096,1024] bf16
  unsigned short* qkv   = (unsigned short*)(ws + 8*MB);     // 24 MB [4096,3072] bf16
  unsigned short* ob    = (unsigned short*)(ws + 32*MB);    // 8 MB  [4096,1024] bf16
  float*          x1    = (float*)(ws + 40*MB);             // 16 MB [4096,1024] fp32
  unsigned short* f     = (unsigned short*)(ws + 56*MB);    // 32 MB [4096,4096] bf16
  unsigned short* wqkvb = (unsigned short*)(ws + 88*MB);    // 6 MB
  unsigned short* wprojb= (unsigned short*)(ws + 94*MB);    // 2 MB
  unsigned short* wfc1b = (unsigned short*)(ws + 96*MB);    // 8 MB
  unsigned short* wfc2b = (unsigned short*)(ws + 104*MB);   // 8 MB

  cvt_bf16<<<3072, 256, 0, stream>>>(w_qkv,  wqkvb,  3072*1024/4);
  cvt_bf16<<<1024, 256, 0, stream>>>(w_proj, wprojb, 1024*1024/4);
  cvt_bf16<<<4096, 256, 0, stream>>>(w_fc1,  wfc1b,  4096*1024/4);
  cvt_bf16<<<4096, 256, 0, stream>>>(w_fc2,  wfc2b,  1024*4096/4);

  ln_bf16<<<4096, 256, 0, stream>>>(x, ln1_g, ln1_b, h);
  gemm_bt<128,0><<<dim3(24, 32), 256, 0, stream>>>(h, wqkvb, b_qkv, nullptr, qkv, 4096, 3072, 1024);
  attn_fwd<<<dim3(32, 32), 256, 0, stream>>>(qkv, ob);
  gemm_bt<64,2><<<dim3(8, 64), 256, 0, stream>>>(ob, wprojb, b_proj, x, x1, 4096, 1024, 1024);
  ln_bf16<<<4096, 256, 0, stream>>>(x1, ln2_g, ln2_b, h);
  gemm_bt<128,1><<<dim3(32, 32), 256, 0, stream>>>(h, wfc1b, b_fc1, nullptr, f, 4096, 4096, 1024);
  gemm_bt<64,2><<<dim3(8, 64), 256, 0, stream>>>(f, wfc2b, b_fc2, x1, out, 4096, 1024, 4096);
}

// Round 4
// 304.078 us; speedup vs baseline: 1.4890x; 1.0383x over previous
//
#include <hip/hip_runtime.h>

typedef __attribute__((ext_vector_type(8))) short short8;
typedef __attribute__((ext_vector_type(4))) float f32x4;

static __device__ __forceinline__ unsigned short f2bf(float f){
  unsigned u = __float_as_uint(f);
  u += 0x7FFF + ((u >> 16) & 1);
  return (unsigned short)(u >> 16);
}

#define GL16(g, l) __builtin_amdgcn_global_load_lds( \
    (const __attribute__((address_space(1))) void*)(g), \
    (__attribute__((address_space(3))) void*)(l), 16, 0, 0)

// ---------------- fp32 -> bf16 convert (all 4 weights, one launch) ----------------
__global__ __launch_bounds__(256) void cvt_all(
    const float* __restrict__ a0, const float* __restrict__ a1,
    const float* __restrict__ a2, const float* __restrict__ a3,
    unsigned short* __restrict__ o0, unsigned short* __restrict__ o1,
    unsigned short* __restrict__ o2, unsigned short* __restrict__ o3){
  int i = blockIdx.x * 256 + threadIdx.x;
  const float* src; unsigned short* dst; int off;
  if (i < 786432)       { src = a0; dst = o0; off = i; }
  else if (i < 1048576) { src = a1; dst = o1; off = i - 786432; }
  else if (i < 2097152) { src = a2; dst = o2; off = i - 1048576; }
  else                  { src = a3; dst = o3; off = i - 2097152; }
  float4 v = reinterpret_cast<const float4*>(src)[off];
  ushort4 o;
  o.x = f2bf(v.x); o.y = f2bf(v.y); o.z = f2bf(v.z); o.w = f2bf(v.w);
  reinterpret_cast<ushort4*>(dst)[off] = o;
}

// ---------------- LayerNorm fp32 -> bf16 ----------------
__global__ __launch_bounds__(256) void ln_bf16(const float* __restrict__ x,
    const float* __restrict__ g, const float* __restrict__ b,
    unsigned short* __restrict__ out){
  int row = blockIdx.x, t = threadIdx.x;
  const float* xr = x + (size_t)row * 1024;
  float4 xv = reinterpret_cast<const float4*>(xr)[t];
  float s  = xv.x + xv.y + xv.z + xv.w;
  float sq = xv.x*xv.x + xv.y*xv.y + xv.z*xv.z + xv.w*xv.w;
  #pragma unroll
  for (int m = 32; m >= 1; m >>= 1){ s += __shfl_xor(s, m); sq += __shfl_xor(sq, m); }
  __shared__ float ss[4], ssq[4];
  int w = t >> 6, lane = t & 63;
  if (lane == 0){ ss[w] = s; ssq[w] = sq; }
  __syncthreads();
  s  = ss[0] + ss[1] + ss[2] + ss[3];
  sq = ssq[0] + ssq[1] + ssq[2] + ssq[3];
  float mu = s * (1.f/1024.f);
  float rs = rsqrtf(sq * (1.f/1024.f) - mu*mu + 1e-5f);
  float4 gv = reinterpret_cast<const float4*>(g)[t];
  float4 bv = reinterpret_cast<const float4*>(b)[t];
  ushort4 o;
  o.x = f2bf((xv.x - mu) * rs * gv.x + bv.x);
  o.y = f2bf((xv.y - mu) * rs * gv.y + bv.y);
  o.z = f2bf((xv.z - mu) * rs * gv.z + bv.z);
  o.w = f2bf((xv.w - mu) * rs * gv.w + bv.w);
  reinterpret_cast<ushort4*>(out + (size_t)row * 1024)[t] = o;
}

// ---------------- GEMM: C[M,N] = epi(A[M,K] * B[N,K]^T + bias) ----------------
// TM x 128 tile, BK=64, 4 waves, global_load_lds staging (m97 structure).
// EPI 0: bf16 out; 1: bf16 out + exact GELU; 2: fp32 out + residual add
template<int TM, int EPI>
__global__ __launch_bounds__(256) void gemm_bt(
    const unsigned short* __restrict__ A,
    const unsigned short* __restrict__ B,
    const float* __restrict__ bias,
    const float* __restrict__ resid,
    void* __restrict__ C,
    int M, int N, int K)
{
  constexpr int MR = TM / 32;           // row fragments per wave
  __shared__ __attribute__((aligned(16))) short As[TM * 64];
  __shared__ __attribute__((aligned(16))) short Bs[128 * 64];
  int tid = threadIdx.x;
  int lane = tid & 63, wave = tid >> 6;
  int wm = wave >> 1, wn = wave & 1;
  int l15 = lane & 15, hi = lane >> 4;
  int bm = blockIdx.y * TM, bn = blockIdx.x * 128;
  int lr = lane >> 3, lseg = lane & 7;   // staging: 8 rows x 8 segs per load
  f32x4 acc[MR][4] = {};
  for (int k0 = 0; k0 < K; k0 += 64){
    __syncthreads();
    #pragma unroll
    for (int j = 0; j < TM / 32; j++){
      int br = (wave * (TM / 32) + j) * 8;
      GL16(A + (size_t)(bm + br + lr) * K + k0 + lseg * 8, &As[br * 64]);
    }
    #pragma unroll
    for (int j = 0; j < 4; j++){
      int br = (wave * 4 + j) * 8;
      GL16(B + (size_t)(bn + br + lr) * K + k0 + lseg * 8, &Bs[br * 64]);
    }
    __syncthreads();
    #pragma unroll
    for (int kk = 0; kk < 64; kk += 32){
      short8 af[MR], bf[4];
      #pragma unroll
      for (int m = 0; m < MR; m++)
        af[m] = *reinterpret_cast<const short8*>(&As[(wm*(TM/2) + m*16 + l15) * 64 + kk + hi*8]);
      #pragma unroll
      for (int n = 0; n < 4; n++)
        bf[n] = *reinterpret_cast<const short8*>(&Bs[(wn*64 + n*16 + l15) * 64 + kk + hi*8]);
      #pragma unroll
      for (int m = 0; m < MR; m++)
        #pragma unroll
        for (int n = 0; n < 4; n++)
          acc[m][n] = __builtin_amdgcn_mfma_f32_16x16x32_bf16(af[m], bf[n], acc[m][n], 0, 0, 0);
    }
  }
  #pragma unroll
  for (int m = 0; m < MR; m++){
    int row = bm + wm*(TM/2) + m*16 + hi*4;
    #pragma unroll
    for (int n = 0; n < 4; n++){
      int col = bn + wn*64 + n*16 + l15;
      float bv = bias[col];
      #pragma unroll
      for (int j = 0; j < 4; j++){
        float v = acc[m][n][j] + bv;
        int r = row + j;
        if (EPI == 1) v = 0.5f * v * (1.f + erff(v * 0.70710678118654752f));
        if (EPI == 2){
          ((float*)C)[(size_t)r * N + col] = v + resid[(size_t)r * N + col];
        } else {
          ((unsigned short*)C)[(size_t)r * N + col] = f2bf(v);
        }
      }
    }
  }
}

// ---------------- Flash attention (swapped QK^T, S^T lane-local softmax) ----------------
// qkv: [B*2048, 3072] bf16 rows = [q 1024 | k 1024 | v 1024], head-major inside; o: [B*2048,1024]
// 1-D grid of 1024 blocks, XCD-swizzled so 4 heads share each XCD's L2.
__global__ __launch_bounds__(256) void attn_fwd(const unsigned short* __restrict__ qkv,
                                                unsigned short* __restrict__ o){
  __shared__ __attribute__((aligned(16))) short K_lds[2][64*64];
  __shared__ __attribute__((aligned(16))) short V_lds[2][64*64];   // V^T
  __shared__ __attribute__((aligned(16))) short P_lds[4][16*64];
  int tid = threadIdx.x, wave = tid >> 6, lane = tid & 63;
  int l15 = lane & 15, hi = lane >> 4, l7 = l15 & 7;
  int bid = blockIdx.x;
  int swz = (bid & 7) * 128 + (bid >> 3);   // bijective: 4 consecutive bh per XCD
  int qt = swz & 31, bh = swz >> 5;
  int b = bh >> 4, h = bh & 15;
  const unsigned short* qbase = qkv + (size_t)b * 2048 * 3072 + h * 64;
  const unsigned short* kbase = qbase + 1024;
  const unsigned short* vbase = qbase + 2048;
  int qrow = qt * 64 + wave * 16 + l15;
  short8 qf0 = *(const short8*)(qbase + (size_t)qrow * 3072 + hi * 8);
  short8 qf1 = *(const short8*)(qbase + (size_t)qrow * 3072 + 32 + hi * 8);
  // fold softmax scale 0.125 into Q (exact in bf16: exponent -3)
  #pragma unroll
  for (int j = 0; j < 8; j++){
    float q0 = __uint_as_float((unsigned)(unsigned short)qf0[j] << 16) * 0.125f;
    float q1 = __uint_as_float((unsigned)(unsigned short)qf1[j] << 16) * 0.125f;
    qf0[j] = (short)f2bf(q0);
    qf1[j] = (short)f2bf(q1);
  }
  int kp = tid & 31, ds8 = tid >> 5;
  int vcg = kp >> 2, vwi = (2 * kp) & 7;
  float m_r = -1e30f, l_r = 0.f;
  f32x4 accO[4] = {};
  short* Pw = &P_lds[wave][0];

  // prologue: stage tile 0 into buffer 0
  {
    short8 kv0[2], vv0, vv1;
    #pragma unroll
    for (int r = 0; r < 2; r++){
      int g = r * 256 + tid, row = g >> 3, cg = g & 7;
      kv0[r] = *(const short8*)(kbase + (size_t)row * 3072 + cg * 8);
    }
    const unsigned short* vr = vbase + (size_t)(2 * kp) * 3072 + ds8 * 8;
    vv0 = *(const short8*)vr; vv1 = *(const short8*)(vr + 3072);
    #pragma unroll
    for (int r = 0; r < 2; r++){
      int g = r * 256 + tid, row = g >> 3, cg = g & 7;
      *(short8*)(&K_lds[0][row * 64 + ((cg ^ (row & 7)) << 3)]) = kv0[r];
    }
    unsigned* Vw = (unsigned*)&V_lds[0][0];
    #pragma unroll
    for (int j = 0; j < 8; j++){
      int d = ds8 * 8 + j;
      int sa = d * 64 + ((vcg ^ (d & 7)) << 3) + vwi;
      Vw[sa >> 1] = (unsigned)(unsigned short)vv0[j] | ((unsigned)(unsigned short)vv1[j] << 16);
    }
    __syncthreads();
  }

  for (int t = 0; t < 32; t++){
    int cur = t & 1;
    const short* Kc = &K_lds[cur][0];
    const short* Vc = &V_lds[cur][0];
    // issue next-tile global loads early (T14: latency hides under compute)
    short8 kv0, kv1, vv0, vv1;
    if (t < 31){
      int kt = (t + 1) * 64;
      { int g = tid,       row = g >> 3, cg = g & 7;
        kv0 = *(const short8*)(kbase + (size_t)(kt + row) * 3072 + cg * 8); }
      { int g = 256 + tid, row = g >> 3, cg = g & 7;
        kv1 = *(const short8*)(kbase + (size_t)(kt + row) * 3072 + cg * 8); }
      const unsigned short* vr = vbase + (size_t)(kt + 2 * kp) * 3072 + ds8 * 8;
      vv0 = *(const short8*)vr; vv1 = *(const short8*)(vr + 3072);
    }
    // S^T[k][q] = sum_d K[k][d] Q[q][d]   (S pre-scaled via Q)
    f32x4 sacc[4];
    __builtin_amdgcn_s_setprio(1);
    #pragma unroll
    for (int kb = 0; kb < 4; kb++){
      f32x4 s = {};
      short8 ka = *(const short8*)(Kc + (kb * 16 + l15) * 64 + ((hi ^ l7) << 3));
      s = __builtin_amdgcn_mfma_f32_16x16x32_bf16(ka, qf0, s, 0, 0, 0);
      short8 kb_ = *(const short8*)(Kc + (kb * 16 + l15) * 64 + (((4 + hi) ^ l7) << 3));
      s = __builtin_amdgcn_mfma_f32_16x16x32_bf16(kb_, qf1, s, 0, 0, 0);
      sacc[kb] = s;
    }
    __builtin_amdgcn_s_setprio(0);
    // per-lane softmax: 16 k-values in-lane, q = l15; cross-hi via 2 shuffles
    float sv[16];
    #pragma unroll
    for (int kb = 0; kb < 4; kb++)
      #pragma unroll
      for (int r2 = 0; r2 < 4; r2++) sv[kb * 4 + r2] = sacc[kb][r2];
    float m01 = fmaxf(fmaxf(sv[0], sv[1]), fmaxf(sv[2], sv[3]));
    float m23 = fmaxf(fmaxf(sv[4], sv[5]), fmaxf(sv[6], sv[7]));
    float m45 = fmaxf(fmaxf(sv[8], sv[9]), fmaxf(sv[10], sv[11]));
    float m67 = fmaxf(fmaxf(sv[12], sv[13]), fmaxf(sv[14], sv[15]));
    float mt = fmaxf(fmaxf(m01, m23), fmaxf(m45, m67));
    mt = fmaxf(mt, __shfl_xor(mt, 16));
    mt = fmaxf(mt, __shfl_xor(mt, 32));
    // defer-max (T13): only rescale when the running max grew by > 8
    if (!__all(mt - m_r <= 8.f)){
      float mn = fmaxf(m_r, mt);
      float corr = __expf(m_r - mn);
      m_r = mn;
      l_r *= corr;
      #pragma unroll
      for (int db = 0; db < 4; db++)
        #pragma unroll
        for (int r2 = 0; r2 < 4; r2++) accO[db][r2] *= corr;
    }
    float rs = 0.f;
    unsigned pu[8];
    #pragma unroll
    for (int i = 0; i < 16; i += 2){
      float p0 = __expf(sv[i] - m_r), p1 = __expf(sv[i + 1] - m_r);
      rs += p0 + p1;
      unsigned pk;
      asm("v_cvt_pk_bf16_f32 %0, %1, %2" : "=v"(pk) : "v"(p0), "v"(p1));
      pu[i >> 1] = pk;
    }
    rs += __shfl_xor(rs, 16);
    rs += __shfl_xor(rs, 32);
    l_r += rs;
    // write P[q=l15][k]: 4x ds_write_b64, swizzled
    #pragma unroll
    for (int kb = 0; kb < 4; kb++){
      int sa = l15 * 64 + ((((kb << 1) | (hi >> 1)) ^ l7) << 3) + ((hi & 1) << 2);
      *(uint2*)(Pw + sa) = make_uint2(pu[kb * 2], pu[kb * 2 + 1]);
    }
    // O^T[d][q] += sum_k V^T[d][k] P[q][k]
    __builtin_amdgcn_s_setprio(1);
    #pragma unroll
    for (int kb2 = 0; kb2 < 2; kb2++){
      short8 pf = *(const short8*)(Pw + l15 * 64 + ((((kb2 << 2) | hi) ^ l7) << 3));
      #pragma unroll
      for (int db = 0; db < 4; db++){
        short8 vf = *(const short8*)(Vc + (db * 16 + l15) * 64 + ((((kb2 << 2) | hi) ^ l7) << 3));
        accO[db] = __builtin_amdgcn_mfma_f32_16x16x32_bf16(vf, pf, accO[db], 0, 0, 0);
      }
    }
    __builtin_amdgcn_s_setprio(0);
    // write next tile to LDS, single barrier
    if (t < 31){
      int nxt = cur ^ 1;
      { int g = tid,       row = g >> 3, cg = g & 7;
        *(short8*)(&K_lds[nxt][row * 64 + ((cg ^ (row & 7)) << 3)]) = kv0; }
      { int g = 256 + tid, row = g >> 3, cg = g & 7;
        *(short8*)(&K_lds[nxt][row * 64 + ((cg ^ (row & 7)) << 3)]) = kv1; }
      unsigned* Vw = (unsigned*)&V_lds[nxt][0];
      #pragma unroll
      for (int j = 0; j < 8; j++){
        int d = ds8 * 8 + j;
        int sa = d * 64 + ((vcg ^ (d & 7)) << 3) + vwi;
        Vw[sa >> 1] = (unsigned)(unsigned short)vv0[j] | ((unsigned)(unsigned short)vv1[j] << 16);
      }
      __syncthreads();
    }
  }
  // epilogue: lane holds O^T[d = db*16+hi*4+r][q = l15]
  float inv = 1.f / l_r;
  unsigned short* ob = o + (size_t)(b * 2048 + qt * 64 + wave * 16 + l15) * 1024 + h * 64;
  #pragma unroll
  for (int db = 0; db < 4; db++){
    ushort4 w;
    w.x = f2bf(accO[db][0] * inv);
    w.y = f2bf(accO[db][1] * inv);
    w.z = f2bf(accO[db][2] * inv);
    w.w = f2bf(accO[db][3] * inv);
    *(ushort4*)(ob + db * 16 + hi * 4) = w;
  }
}

extern "C" void kernel_launch(void* const* d_in, const int* in_sizes, int n_in,
                              void* d_out, int out_size, void* d_ws, size_t ws_size,
                              hipStream_t stream){
  const float* x      = (const float*)d_in[0];
  const float* ln1_g  = (const float*)d_in[1];
  const float* ln1_b  = (const float*)d_in[2];
  const float* w_qkv  = (const float*)d_in[3];
  const float* b_qkv  = (const float*)d_in[4];
  const float* w_proj = (const float*)d_in[5];
  const float* b_proj = (const float*)d_in[6];
  const float* ln2_g  = (const float*)d_in[7];
  const float* ln2_b  = (const float*)d_in[8];
  const float* w_fc1  = (const float*)d_in[9];
  const float* b_fc1  = (const float*)d_in[10];
  const float* w_fc2  = (const float*)d_in[11];
  const float* b_fc2  = (const float*)d_in[12];
  float* out = (float*)d_out;
  char* ws = (char*)d_ws;
  const size_t MB = 1024 * 1024;
  unsigned short* h     = (unsigned short*)(ws);            // 8 MB  [4096,1024] bf16
  unsigned short* qkv   = (unsigned short*)(ws + 8*MB);     // 24 MB [4096,3072] bf16
  unsigned short* ob    = (unsigned short*)(ws + 32*MB);    // 8 MB  [4096,1024] bf16
  float*          x1    = (float*)(ws + 40*MB);             // 16 MB [4096,1024] fp32
  unsigned short* f     = (unsigned short*)(ws + 56*MB);    // 32 MB [4096,4096] bf16
  unsigned short* wqkvb = (unsigned short*)(ws + 88*MB);    // 6 MB
  unsigned short* wprojb= (unsigned short*)(ws + 94*MB);    // 2 MB
  unsigned short* wfc1b = (unsigned short*)(ws + 96*MB);    // 8 MB
  unsigned short* wfc2b = (unsigned short*)(ws + 104*MB);   // 8 MB

  cvt_all<<<12288, 256, 0, stream>>>(w_qkv, w_proj, w_fc1, w_fc2,
                                     wqkvb, wprojb, wfc1b, wfc2b);

  ln_bf16<<<4096, 256, 0, stream>>>(x, ln1_g, ln1_b, h);
  gemm_bt<128,0><<<dim3(24, 32), 256, 0, stream>>>(h, wqkvb, b_qkv, nullptr, qkv, 4096, 3072, 1024);
  attn_fwd<<<1024, 256, 0, stream>>>(qkv, ob);
  gemm_bt<64,2><<<dim3(8, 64), 256, 0, stream>>>(ob, wprojb, b_proj, x, x1, 4096, 1024, 1024);
  ln_bf16<<<4096, 256, 0, stream>>>(x1, ln2_g, ln2_b, h);
  gemm_bt<128,1><<<dim3(32, 32), 256, 0, stream>>>(h, wfc1b, b_fc1, nullptr, f, 4096, 4096, 1024);
  gemm_bt<64,2><<<dim3(8, 64), 256, 0, stream>>>(f, wfc2b, b_fc2, x1, out, 4096, 1024, 4096);
}

// Round 5
// 275.404 us; speedup vs baseline: 1.6440x; 1.1041x over previous
//
#include <hip/hip_runtime.h>

typedef __attribute__((ext_vector_type(8))) short short8;
typedef __attribute__((ext_vector_type(4))) float f32x4;

static __device__ __forceinline__ unsigned short f2bf(float f){
  unsigned u = __float_as_uint(f);
  u += 0x7FFF + ((u >> 16) & 1);
  return (unsigned short)(u >> 16);
}

static __device__ __forceinline__ f32x4 MF(short8 a, short8 b, f32x4 c){
  return __builtin_amdgcn_mfma_f32_16x16x32_bf16(a, b, c, 0, 0, 0);
}

#define GL16(g, l) __builtin_amdgcn_global_load_lds( \
    (const __attribute__((address_space(1))) void*)(g), \
    (__attribute__((address_space(3))) void*)(l), 16, 0, 0)

#define SBAR { __builtin_amdgcn_sched_barrier(0); __builtin_amdgcn_s_barrier(); __builtin_amdgcn_sched_barrier(0); }

// ---------------- fp32 -> bf16 convert (all 4 weights, one launch) ----------------
__global__ __launch_bounds__(256) void cvt_all(
    const float* __restrict__ a0, const float* __restrict__ a1,
    const float* __restrict__ a2, const float* __restrict__ a3,
    unsigned short* __restrict__ o0, unsigned short* __restrict__ o1,
    unsigned short* __restrict__ o2, unsigned short* __restrict__ o3){
  int i = blockIdx.x * 256 + threadIdx.x;
  const float* src; unsigned short* dst; int off;
  if (i < 786432)       { src = a0; dst = o0; off = i; }
  else if (i < 1048576) { src = a1; dst = o1; off = i - 786432; }
  else if (i < 2097152) { src = a2; dst = o2; off = i - 1048576; }
  else                  { src = a3; dst = o3; off = i - 2097152; }
  float4 v = reinterpret_cast<const float4*>(src)[off];
  ushort4 o;
  o.x = f2bf(v.x); o.y = f2bf(v.y); o.z = f2bf(v.z); o.w = f2bf(v.w);
  reinterpret_cast<ushort4*>(dst)[off] = o;
}

// ---------------- LayerNorm fp32 -> bf16 ----------------
__global__ __launch_bounds__(256) void ln_bf16(const float* __restrict__ x,
    const float* __restrict__ g, const float* __restrict__ b,
    unsigned short* __restrict__ out){
  int row = blockIdx.x, t = threadIdx.x;
  const float* xr = x + (size_t)row * 1024;
  float4 xv = reinterpret_cast<const float4*>(xr)[t];
  float s  = xv.x + xv.y + xv.z + xv.w;
  float sq = xv.x*xv.x + xv.y*xv.y + xv.z*xv.z + xv.w*xv.w;
  #pragma unroll
  for (int m = 32; m >= 1; m >>= 1){ s += __shfl_xor(s, m); sq += __shfl_xor(sq, m); }
  __shared__ float ss[4], ssq[4];
  int w = t >> 6, lane = t & 63;
  if (lane == 0){ ss[w] = s; ssq[w] = sq; }
  __syncthreads();
  s  = ss[0] + ss[1] + ss[2] + ss[3];
  sq = ssq[0] + ssq[1] + ssq[2] + ssq[3];
  float mu = s * (1.f/1024.f);
  float rs = rsqrtf(sq * (1.f/1024.f) - mu*mu + 1e-5f);
  float4 gv = reinterpret_cast<const float4*>(g)[t];
  float4 bv = reinterpret_cast<const float4*>(b)[t];
  ushort4 o;
  o.x = f2bf((xv.x - mu) * rs * gv.x + bv.x);
  o.y = f2bf((xv.y - mu) * rs * gv.y + bv.y);
  o.z = f2bf((xv.z - mu) * rs * gv.z + bv.z);
  o.w = f2bf((xv.w - mu) * rs * gv.w + bv.w);
  reinterpret_cast<ushort4*>(out + (size_t)row * 1024)[t] = o;
}

// ---------------- 256x256 8-phase GEMM (m201 template, plain HIP) ----------------
// C[M,N] = epi(A[M,K] * B[N,K]^T + bias). 8 waves 2Mx4N, BK=64, 128KB LDS,
// st_16x32 swizzle both-sides, counted vmcnt(4) at phases 4/8 only.
// EPI 0: bf16 out; 1: bf16 out + exact GELU
template<int EPI>
__global__ __launch_bounds__(512, 2) void gemm8p(
    const unsigned short* __restrict__ A,
    const unsigned short* __restrict__ B,
    const float* __restrict__ bias,
    void* __restrict__ C,
    int M, int N, int K)
{
  __shared__ __attribute__((aligned(16))) short As[2 * 256 * 64];
  __shared__ __attribute__((aligned(16))) short Bs[2 * 256 * 64];
  const int NT = K >> 6;
  int tid = threadIdx.x, lane = tid & 63, wave = tid >> 6;
  int wm = wave >> 2, wn = wave & 3;
  int l15 = lane & 15, hi = lane >> 4;
  int hi2 = hi ^ (((l15 >> 2) & 1) << 1);            // read-side st_16x32 swizzle
  int bm = blockIdx.y * 256, bn = blockIdx.x * 256;
  int lr = lane >> 3;
  int sg8 = ((lane & 7) ^ ((lane >> 5) << 1)) * 8;   // source-side pre-swizzle
  int rb0 = wave * 16;

  f32x4 acc[8][4] = {};
  short8 aR[4][2], bA[2][2], bB[2][2];

  auto stage = [&](int T, int h){
    if (T >= NT) return;
    const unsigned short* src = (h < 2) ? (A + (size_t)(bm + ((h & 1) << 7)) * K)
                                        : (B + (size_t)(bn + ((h & 1) << 7)) * K);
    short* dst = ((h < 2) ? As : Bs) + ((T & 1) << 14) + ((h & 1) << 13);
    const unsigned short* s = src + (size_t)(rb0 + lr) * K + (T << 6) + sg8;
    GL16(s, dst + rb0 * 64);
    GL16(s + (size_t)8 * K, dst + (rb0 + 8) * 64);
  };
  auto LDA = [&](const short* Ab, int m, int kk){
    int R = wm * 128 + m * 16 + l15;
    return *(const short8*)(Ab + R * 64 + kk * 32 + hi2 * 8);
  };
  auto LDB = [&](const short* Bb, int n, int kk){
    int R = wn * 64 + n * 16 + l15;
    return *(const short8*)(Bb + R * 64 + kk * 32 + hi2 * 8);
  };

  // prologue: tile0 fully + tile1 A-halves; leave 2 halves (4 loads) in flight
  stage(0, 0); stage(0, 1); stage(0, 2); stage(0, 3);
  stage(1, 0); stage(1, 1);
  asm volatile("s_waitcnt vmcnt(4)" ::: "memory");
  SBAR;

  for (int i = 0; i < (NT >> 1); ++i){
    int t0 = 2 * i, t1 = t0 + 1;
    const short* A0 = As;            const short* B0 = Bs;
    const short* A1 = As + 16384;    const short* B1 = Bs + 16384;
    // ---- phase 1: q(0,0) of t0; stage (t1, B0-half) ----
    #pragma unroll
    for (int m = 0; m < 4; m++){ aR[m][0] = LDA(A0, m, 0); aR[m][1] = LDA(A0, m, 1); }
    #pragma unroll
    for (int n = 0; n < 2; n++){ bA[n][0] = LDB(B0, n, 0); bA[n][1] = LDB(B0, n, 1); }
    __builtin_amdgcn_sched_barrier(0);
    stage(t1, 2);
    SBAR;
    __builtin_amdgcn_s_setprio(1);
    #pragma unroll
    for (int m = 0; m < 4; m++)
      #pragma unroll
      for (int n = 0; n < 2; n++)
        #pragma unroll
        for (int kk = 0; kk < 2; kk++) acc[m][n] = MF(aR[m][kk], bA[n][kk], acc[m][n]);
    __builtin_amdgcn_s_setprio(0);
    SBAR;
    // ---- phase 2: q(0,1) of t0; stage (t1, B1-half) ----
    #pragma unroll
    for (int n = 0; n < 2; n++){ bB[n][0] = LDB(B0, n + 2, 0); bB[n][1] = LDB(B0, n + 2, 1); }
    __builtin_amdgcn_sched_barrier(0);
    stage(t1, 3);
    SBAR;
    __builtin_amdgcn_s_setprio(1);
    #pragma unroll
    for (int m = 0; m < 4; m++)
      #pragma unroll
      for (int n = 0; n < 2; n++)
        #pragma unroll
        for (int kk = 0; kk < 2; kk++) acc[m][n + 2] = MF(aR[m][kk], bB[n][kk], acc[m][n + 2]);
    __builtin_amdgcn_s_setprio(0);
    SBAR;
    // ---- phase 3: q(1,0) of t0; stage (t0+2, A0-half) ----
    #pragma unroll
    for (int m = 0; m < 4; m++){ aR[m][0] = LDA(A0, m + 4, 0); aR[m][1] = LDA(A0, m + 4, 1); }
    __builtin_amdgcn_sched_barrier(0);
    stage(t0 + 2, 0);
    SBAR;
    __builtin_amdgcn_s_setprio(1);
    #pragma unroll
    for (int m = 0; m < 4; m++)
      #pragma unroll
      for (int n = 0; n < 2; n++)
        #pragma unroll
        for (int kk = 0; kk < 2; kk++) acc[m + 4][n] = MF(aR[m][kk], bA[n][kk], acc[m + 4][n]);
    __builtin_amdgcn_s_setprio(0);
    SBAR;
    // ---- phase 4: q(1,1) of t0; stage (t0+2, A1-half); vmcnt(4) ----
    stage(t0 + 2, 1);
    SBAR;
    __builtin_amdgcn_s_setprio(1);
    #pragma unroll
    for (int m = 0; m < 4; m++)
      #pragma unroll
      for (int n = 0; n < 2; n++)
        #pragma unroll
        for (int kk = 0; kk < 2; kk++) acc[m + 4][n + 2] = MF(aR[m][kk], bB[n][kk], acc[m + 4][n + 2]);
    __builtin_amdgcn_s_setprio(0);
    asm volatile("s_waitcnt vmcnt(4)" ::: "memory");
    SBAR;
    // ---- phase 5: q(0,0) of t1; stage (t0+2, B0-half) ----
    #pragma unroll
    for (int m = 0; m < 4; m++){ aR[m][0] = LDA(A1, m, 0); aR[m][1] = LDA(A1, m, 1); }
    #pragma unroll
    for (int n = 0; n < 2; n++){ bA[n][0] = LDB(B1, n, 0); bA[n][1] = LDB(B1, n, 1); }
    __builtin_amdgcn_sched_barrier(0);
    stage(t0 + 2, 2);
    SBAR;
    __builtin_amdgcn_s_setprio(1);
    #pragma unroll
    for (int m = 0; m < 4; m++)
      #pragma unroll
      for (int n = 0; n < 2; n++)
        #pragma unroll
        for (int kk = 0; kk < 2; kk++) acc[m][n] = MF(aR[m][kk], bA[n][kk], acc[m][n]);
    __builtin_amdgcn_s_setprio(0);
    SBAR;
    // ---- phase 6: q(0,1) of t1; stage (t0+2, B1-half) ----
    #pragma unroll
    for (int n = 0; n < 2; n++){ bB[n][0] = LDB(B1, n + 2, 0); bB[n][1] = LDB(B1, n + 2, 1); }
    __builtin_amdgcn_sched_barrier(0);
    stage(t0 + 2, 3);
    SBAR;
    __builtin_amdgcn_s_setprio(1);
    #pragma unroll
    for (int m = 0; m < 4; m++)
      #pragma unroll
      for (int n = 0; n < 2; n++)
        #pragma unroll
        for (int kk = 0; kk < 2; kk++) acc[m][n + 2] = MF(aR[m][kk], bB[n][kk], acc[m][n + 2]);
    __builtin_amdgcn_s_setprio(0);
    SBAR;
    // ---- phase 7: q(1,0) of t1; stage (t0+3, A0-half) ----
    #pragma unroll
    for (int m = 0; m < 4; m++){ aR[m][0] = LDA(A1, m + 4, 0); aR[m][1] = LDA(A1, m + 4, 1); }
    __builtin_amdgcn_sched_barrier(0);
    stage(t0 + 3, 0);
    SBAR;
    __builtin_amdgcn_s_setprio(1);
    #pragma unroll
    for (int m = 0; m < 4; m++)
      #pragma unroll
      for (int n = 0; n < 2; n++)
        #pragma unroll
        for (int kk = 0; kk < 2; kk++) acc[m + 4][n] = MF(aR[m][kk], bA[n][kk], acc[m + 4][n]);
    __builtin_amdgcn_s_setprio(0);
    SBAR;
    // ---- phase 8: q(1,1) of t1; stage (t0+3, A1-half); vmcnt(4) ----
    stage(t0 + 3, 1);
    SBAR;
    __builtin_amdgcn_s_setprio(1);
    #pragma unroll
    for (int m = 0; m < 4; m++)
      #pragma unroll
      for (int n = 0; n < 2; n++)
        #pragma unroll
        for (int kk = 0; kk < 2; kk++) acc[m + 4][n + 2] = MF(aR[m][kk], bB[n][kk], acc[m + 4][n + 2]);
    __builtin_amdgcn_s_setprio(0);
    asm volatile("s_waitcnt vmcnt(4)" ::: "memory");
    SBAR;
  }

  // epilogue
  #pragma unroll
  for (int m = 0; m < 8; m++){
    int row = bm + wm * 128 + m * 16 + hi * 4;
    #pragma unroll
    for (int n = 0; n < 4; n++){
      int col = bn + wn * 64 + n * 16 + l15;
      float bv = bias[col];
      #pragma unroll
      for (int j = 0; j < 4; j++){
        float v = acc[m][n][j] + bv;
        if (EPI == 1) v = 0.5f * v * (1.f + erff(v * 0.70710678118654752f));
        ((unsigned short*)C)[(size_t)(row + j) * N + col] = f2bf(v);
      }
    }
  }
}

// ---------------- GEMM: C[M,N] = epi(A[M,K] * B[N,K]^T + bias) ----------------
// TM x 128 tile, BK=64, 4 waves, global_load_lds staging (m97 structure).
// EPI 2: fp32 out + residual add
template<int TM, int EPI>
__global__ __launch_bounds__(256) void gemm_bt(
    const unsigned short* __restrict__ A,
    const unsigned short* __restrict__ B,
    const float* __restrict__ bias,
    const float* __restrict__ resid,
    void* __restrict__ C,
    int M, int N, int K)
{
  constexpr int MR = TM / 32;
  __shared__ __attribute__((aligned(16))) short As[TM * 64];
  __shared__ __attribute__((aligned(16))) short Bs[128 * 64];
  int tid = threadIdx.x;
  int lane = tid & 63, wave = tid >> 6;
  int wm = wave >> 1, wn = wave & 1;
  int l15 = lane & 15, hi = lane >> 4;
  int bm = blockIdx.y * TM, bn = blockIdx.x * 128;
  int lr = lane >> 3, lseg = lane & 7;
  f32x4 acc[MR][4] = {};
  for (int k0 = 0; k0 < K; k0 += 64){
    __syncthreads();
    #pragma unroll
    for (int j = 0; j < TM / 32; j++){
      int br = (wave * (TM / 32) + j) * 8;
      GL16(A + (size_t)(bm + br + lr) * K + k0 + lseg * 8, &As[br * 64]);
    }
    #pragma unroll
    for (int j = 0; j < 4; j++){
      int br = (wave * 4 + j) * 8;
      GL16(B + (size_t)(bn + br + lr) * K + k0 + lseg * 8, &Bs[br * 64]);
    }
    __syncthreads();
    #pragma unroll
    for (int kk = 0; kk < 64; kk += 32){
      short8 af[MR], bf[4];
      #pragma unroll
      for (int m = 0; m < MR; m++)
        af[m] = *reinterpret_cast<const short8*>(&As[(wm*(TM/2) + m*16 + l15) * 64 + kk + hi*8]);
      #pragma unroll
      for (int n = 0; n < 4; n++)
        bf[n] = *reinterpret_cast<const short8*>(&Bs[(wn*64 + n*16 + l15) * 64 + kk + hi*8]);
      #pragma unroll
      for (int m = 0; m < MR; m++)
        #pragma unroll
        for (int n = 0; n < 4; n++)
          acc[m][n] = __builtin_amdgcn_mfma_f32_16x16x32_bf16(af[m], bf[n], acc[m][n], 0, 0, 0);
    }
  }
  #pragma unroll
  for (int m = 0; m < MR; m++){
    int row = bm + wm*(TM/2) + m*16 + hi*4;
    #pragma unroll
    for (int n = 0; n < 4; n++){
      int col = bn + wn*64 + n*16 + l15;
      float bv = bias[col];
      #pragma unroll
      for (int j = 0; j < 4; j++){
        float v = acc[m][n][j] + bv;
        int r = row + j;
        if (EPI == 1) v = 0.5f * v * (1.f + erff(v * 0.70710678118654752f));
        if (EPI == 2){
          ((float*)C)[(size_t)r * N + col] = v + resid[(size_t)r * N + col];
        } else {
          ((unsigned short*)C)[(size_t)r * N + col] = f2bf(v);
        }
      }
    }
  }
}

// ---------------- Flash attention (swapped QK^T, S^T lane-local softmax) ----------------
__global__ __launch_bounds__(256) void attn_fwd(const unsigned short* __restrict__ qkv,
                                                unsigned short* __restrict__ o){
  __shared__ __attribute__((aligned(16))) short K_lds[2][64*64];
  __shared__ __attribute__((aligned(16))) short V_lds[2][64*64];   // V^T
  __shared__ __attribute__((aligned(16))) short P_lds[4][16*64];
  int tid = threadIdx.x, wave = tid >> 6, lane = tid & 63;
  int l15 = lane & 15, hi = lane >> 4, l7 = l15 & 7;
  int bid = blockIdx.x;
  int swz = (bid & 7) * 128 + (bid >> 3);
  int qt = swz & 31, bh = swz >> 5;
  int b = bh >> 4, h = bh & 15;
  const unsigned short* qbase = qkv + (size_t)b * 2048 * 3072 + h * 64;
  const unsigned short* kbase = qbase + 1024;
  const unsigned short* vbase = qbase + 2048;
  int qrow = qt * 64 + wave * 16 + l15;
  short8 qf0 = *(const short8*)(qbase + (size_t)qrow * 3072 + hi * 8);
  short8 qf1 = *(const short8*)(qbase + (size_t)qrow * 3072 + 32 + hi * 8);
  #pragma unroll
  for (int j = 0; j < 8; j++){
    float q0 = __uint_as_float((unsigned)(unsigned short)qf0[j] << 16) * 0.125f;
    float q1 = __uint_as_float((unsigned)(unsigned short)qf1[j] << 16) * 0.125f;
    qf0[j] = (short)f2bf(q0);
    qf1[j] = (short)f2bf(q1);
  }
  int kp = tid & 31, ds8 = tid >> 5;
  int vcg = kp >> 2, vwi = (2 * kp) & 7;
  float m_r = -1e30f, l_r = 0.f;
  f32x4 accO[4] = {};
  short* Pw = &P_lds[wave][0];

  {
    short8 kv0[2], vv0, vv1;
    #pragma unroll
    for (int r = 0; r < 2; r++){
      int g = r * 256 + tid, row = g >> 3, cg = g & 7;
      kv0[r] = *(const short8*)(kbase + (size_t)row * 3072 + cg * 8);
    }
    const unsigned short* vr = vbase + (size_t)(2 * kp) * 3072 + ds8 * 8;
    vv0 = *(const short8*)vr; vv1 = *(const short8*)(vr + 3072);
    #pragma unroll
    for (int r = 0; r < 2; r++){
      int g = r * 256 + tid, row = g >> 3, cg = g & 7;
      *(short8*)(&K_lds[0][row * 64 + ((cg ^ (row & 7)) << 3)]) = kv0[r];
    }
    unsigned* Vw = (unsigned*)&V_lds[0][0];
    #pragma unroll
    for (int j = 0; j < 8; j++){
      int d = ds8 * 8 + j;
      int sa = d * 64 + ((vcg ^ (d & 7)) << 3) + vwi;
      Vw[sa >> 1] = (unsigned)(unsigned short)vv0[j] | ((unsigned)(unsigned short)vv1[j] << 16);
    }
    __syncthreads();
  }

  for (int t = 0; t < 32; t++){
    int cur = t & 1;
    const short* Kc = &K_lds[cur][0];
    const short* Vc = &V_lds[cur][0];
    short8 kv0, kv1, vv0, vv1;
    if (t < 31){
      int kt = (t + 1) * 64;
      { int g = tid,       row = g >> 3, cg = g & 7;
        kv0 = *(const short8*)(kbase + (size_t)(kt + row) * 3072 + cg * 8); }
      { int g = 256 + tid, row = g >> 3, cg = g & 7;
        kv1 = *(const short8*)(kbase + (size_t)(kt + row) * 3072 + cg * 8); }
      const unsigned short* vr = vbase + (size_t)(kt + 2 * kp) * 3072 + ds8 * 8;
      vv0 = *(const short8*)vr; vv1 = *(const short8*)(vr + 3072);
    }
    f32x4 sacc[4];
    __builtin_amdgcn_s_setprio(1);
    #pragma unroll
    for (int kb = 0; kb < 4; kb++){
      f32x4 s = {};
      short8 ka = *(const short8*)(Kc + (kb * 16 + l15) * 64 + ((hi ^ l7) << 3));
      s = __builtin_amdgcn_mfma_f32_16x16x32_bf16(ka, qf0, s, 0, 0, 0);
      short8 kb_ = *(const short8*)(Kc + (kb * 16 + l15) * 64 + (((4 + hi) ^ l7) << 3));
      s = __builtin_amdgcn_mfma_f32_16x16x32_bf16(kb_, qf1, s, 0, 0, 0);
      sacc[kb] = s;
    }
    __builtin_amdgcn_s_setprio(0);
    float sv[16];
    #pragma unroll
    for (int kb = 0; kb < 4; kb++)
      #pragma unroll
      for (int r2 = 0; r2 < 4; r2++) sv[kb * 4 + r2] = sacc[kb][r2];
    float m01 = fmaxf(fmaxf(sv[0], sv[1]), fmaxf(sv[2], sv[3]));
    float m23 = fmaxf(fmaxf(sv[4], sv[5]), fmaxf(sv[6], sv[7]));
    float m45 = fmaxf(fmaxf(sv[8], sv[9]), fmaxf(sv[10], sv[11]));
    float m67 = fmaxf(fmaxf(sv[12], sv[13]), fmaxf(sv[14], sv[15]));
    float mt = fmaxf(fmaxf(m01, m23), fmaxf(m45, m67));
    mt = fmaxf(mt, __shfl_xor(mt, 16));
    mt = fmaxf(mt, __shfl_xor(mt, 32));
    if (!__all(mt - m_r <= 8.f)){
      float mn = fmaxf(m_r, mt);
      float corr = __expf(m_r - mn);
      m_r = mn;
      l_r *= corr;
      #pragma unroll
      for (int db = 0; db < 4; db++)
        #pragma unroll
        for (int r2 = 0; r2 < 4; r2++) accO[db][r2] *= corr;
    }
    float rs = 0.f;
    unsigned pu[8];
    #pragma unroll
    for (int i = 0; i < 16; i += 2){
      float p0 = __expf(sv[i] - m_r), p1 = __expf(sv[i + 1] - m_r);
      rs += p0 + p1;
      unsigned pk;
      asm("v_cvt_pk_bf16_f32 %0, %1, %2" : "=v"(pk) : "v"(p0), "v"(p1));
      pu[i >> 1] = pk;
    }
    rs += __shfl_xor(rs, 16);
    rs += __shfl_xor(rs, 32);
    l_r += rs;
    #pragma unroll
    for (int kb = 0; kb < 4; kb++){
      int sa = l15 * 64 + ((((kb << 1) | (hi >> 1)) ^ l7) << 3) + ((hi & 1) << 2);
      *(uint2*)(Pw + sa) = make_uint2(pu[kb * 2], pu[kb * 2 + 1]);
    }
    __builtin_amdgcn_s_setprio(1);
    #pragma unroll
    for (int kb2 = 0; kb2 < 2; kb2++){
      short8 pf = *(const short8*)(Pw + l15 * 64 + ((((kb2 << 2) | hi) ^ l7) << 3));
      #pragma unroll
      for (int db = 0; db < 4; db++){
        short8 vf = *(const short8*)(Vc + (db * 16 + l15) * 64 + ((((kb2 << 2) | hi) ^ l7) << 3));
        accO[db] = __builtin_amdgcn_mfma_f32_16x16x32_bf16(vf, pf, accO[db], 0, 0, 0);
      }
    }
    __builtin_amdgcn_s_setprio(0);
    if (t < 31){
      int nxt = cur ^ 1;
      { int g = tid,       row = g >> 3, cg = g & 7;
        *(short8*)(&K_lds[nxt][row * 64 + ((cg ^ (row & 7)) << 3)]) = kv0; }
      { int g = 256 + tid, row = g >> 3, cg = g & 7;
        *(short8*)(&K_lds[nxt][row * 64 + ((cg ^ (row & 7)) << 3)]) = kv1; }
      unsigned* Vw = (unsigned*)&V_lds[nxt][0];
      #pragma unroll
      for (int j = 0; j < 8; j++){
        int d = ds8 * 8 + j;
        int sa = d * 64 + ((vcg ^ (d & 7)) << 3) + vwi;
        Vw[sa >> 1] = (unsigned)(unsigned short)vv0[j] | ((unsigned)(unsigned short)vv1[j] << 16);
      }
      __syncthreads();
    }
  }
  float inv = 1.f / l_r;
  unsigned short* ob = o + (size_t)(b * 2048 + qt * 64 + wave * 16 + l15) * 1024 + h * 64;
  #pragma unroll
  for (int db = 0; db < 4; db++){
    ushort4 w;
    w.x = f2bf(accO[db][0] * inv);
    w.y = f2bf(accO[db][1] * inv);
    w.z = f2bf(accO[db][2] * inv);
    w.w = f2bf(accO[db][3] * inv);
    *(ushort4*)(ob + db * 16 + hi * 4) = w;
  }
}

extern "C" void kernel_launch(void* const* d_in, const int* in_sizes, int n_in,
                              void* d_out, int out_size, void* d_ws, size_t ws_size,
                              hipStream_t stream){
  const float* x      = (const float*)d_in[0];
  const float* ln1_g  = (const float*)d_in[1];
  const float* ln1_b  = (const float*)d_in[2];
  const float* w_qkv  = (const float*)d_in[3];
  const float* b_qkv  = (const float*)d_in[4];
  const float* w_proj = (const float*)d_in[5];
  const float* b_proj = (const float*)d_in[6];
  const float* ln2_g  = (const float*)d_in[7];
  const float* ln2_b  = (const float*)d_in[8];
  const float* w_fc1  = (const float*)d_in[9];
  const float* b_fc1  = (const float*)d_in[10];
  const float* w_fc2  = (const float*)d_in[11];
  const float* b_fc2  = (const float*)d_in[12];
  float* out = (float*)d_out;
  char* ws = (char*)d_ws;
  const size_t MB = 1024 * 1024;
  unsigned short* h     = (unsigned short*)(ws);            // 8 MB  [4096,1024] bf16
  unsigned short* qkv   = (unsigned short*)(ws + 8*MB);     // 24 MB [4096,3072] bf16
  unsigned short* ob    = (unsigned short*)(ws + 32*MB);    // 8 MB  [4096,1024] bf16
  float*          x1    = (float*)(ws + 40*MB);             // 16 MB [4096,1024] fp32
  unsigned short* f     = (unsigned short*)(ws + 56*MB);    // 32 MB [4096,4096] bf16
  unsigned short* wqkvb = (unsigned short*)(ws + 88*MB);    // 6 MB
  unsigned short* wprojb= (unsigned short*)(ws + 94*MB);    // 2 MB
  unsigned short* wfc1b = (unsigned short*)(ws + 96*MB);    // 8 MB
  unsigned short* wfc2b = (unsigned short*)(ws + 104*MB);   // 8 MB

  cvt_all<<<12288, 256, 0, stream>>>(w_qkv, w_proj, w_fc1, w_fc2,
                                     wqkvb, wprojb, wfc1b, wfc2b);

  ln_bf16<<<4096, 256, 0, stream>>>(x, ln1_g, ln1_b, h);
  gemm8p<0><<<dim3(12, 16), 512, 0, stream>>>(h, wqkvb, b_qkv, qkv, 4096, 3072, 1024);
  attn_fwd<<<1024, 256, 0, stream>>>(qkv, ob);
  gemm_bt<64,2><<<dim3(8, 64), 256, 0, stream>>>(ob, wprojb, b_proj, x, x1, 4096, 1024, 1024);
  ln_bf16<<<4096, 256, 0, stream>>>(x1, ln2_g, ln2_b, h);
  gemm8p<1><<<dim3(16, 16), 512, 0, stream>>>(h, wfc1b, b_fc1, f, 4096, 4096, 1024);
  gemm_bt<64,2><<<dim3(8, 64), 256, 0, stream>>>(f, wfc2b, b_fc2, x1, out, 4096, 1024, 4096);
}